// Round 6
// baseline (260.483 us; speedup 1.0000x reference)
//
#include <hip/hip_runtime.h>
#include <hip/hip_bf16.h>

// out[b,o,hw] = sum_c W[o,c] * relu(x[b,c,hw]*scale[c] + shift[c])
// B=256, Cin=2112, Cout=192, HW=49, fp32 in HBM, bf16 MFMA internally.
//
// R13: K-SPLIT x6 + fp32 atomicAdd. R8-R11 (LDS-staged, 8 waves/CU) all
// plateau at fused ~55-65us with every pipe <20% busy, invariant to
// barrier count / wave grouping / rolling -> lockstep latency chains at
// 2 waves/SIMD with nothing to overlap. R12 (global gather) proved the
// TA-segment path is worse. Fix: occupancy. 6 K-chunks of 352 ch
// (11 granules); grid 1536 = (chunk, image); 4-wave blocks, ~9 KB LDS,
// VGPR capped 128 -> 4 independent blocks/CU = 16 waves/CU. Each block
// = R9's proven staging (coalesced f32x4 -> BN+ReLU -> swizzled LDS
// tile, one lgkmcnt(0)+s_barrier per granule). Each wave: 48 rows x 64
// cols = 12 MFMA/granule. Partials -> atomicAdd(out), out zeroed via
// hipMemsetAsync (stream-ordered). x still read exactly once chip-wide.

#define CIN    2112
#define COUT   192
#define HWS    49
#define BK     32
#define NCHUNK 6
#define NL     11                  // granules per chunk (352 ch)
#define CCH    (NL * BK)           // 352 channels per chunk
#define NK32   (CIN / BK)          // 66
#define EPSV   1e-5f
#define SLAB   (BK * HWS)          // 1568 elems per granule slab

typedef __bf16 bf16;
typedef __attribute__((ext_vector_type(8))) __bf16 bf16x8;
typedef __attribute__((ext_vector_type(4))) float  f32x4;

// ---------- kernel 1: W fp32 -> bf16 in A-fragment order (unchanged) ----------
__global__ __launch_bounds__(256)
void w_repack_kernel(const float* __restrict__ W, bf16* __restrict__ Wb) {
    const int t = blockIdx.x * 256 + threadIdx.x;       // 66*12*64 = 50688
    if (t >= NK32 * 12 * 64) return;
    const int lane = t & 63;
    const int gmt  = (t >> 6) % 12;
    const int ks   = t / (12 * 64);
    const int row  = gmt * 16 + (lane & 15);
    const int k    = ks * BK + (lane >> 4) * 8;
    const float* src = W + (size_t)row * CIN + k;
    f32x4 a = *(const f32x4*)src;
    f32x4 c = *(const f32x4*)(src + 4);
    bf16x8 o;
    #pragma unroll
    for (int j = 0; j < 4; j++) { o[j] = (bf16)a[j]; o[j + 4] = (bf16)c[j]; }
    *(bf16x8*)(Wb + (size_t)t * 8) = o;
}

// ---------- kernel 2: fused BN+ReLU+pack+GEMM over one K-chunk ----------
__global__ __launch_bounds__(256, 4)
void fused_kernel(const float* __restrict__ x,
                  const float* __restrict__ gamma,
                  const float* __restrict__ beta,
                  const float* __restrict__ rmean,
                  const float* __restrict__ rvar,
                  const bf16* __restrict__ Wb,
                  float* __restrict__ out)
{
    __shared__ float2 ss[CCH + 2];                   // chunk BN params (+pad)
    __shared__ __align__(16) bf16 bt[2][SLAB];       // double-buffered tile

    const int tid = threadIdx.x;
    const int kc  = blockIdx.x >> 8;                 // chunk 0..5
    const int b   = blockIdx.x & 255;                // image
    const int kbase = kc * NL;                       // first granule
    const int cbase = kc * CCH;                      // first channel

    // chunk's BN params -> LDS
    for (int c = tid; c < CCH + 2; c += 256) {
        if (c < CCH) {
            const int gc = cbase + c;
            float inv = rsqrtf(rvar[gc] + EPSV);
            float s   = gamma[gc] * inv;
            ss[c] = make_float2(s, beta[gc] - rmean[gc] * s);
        } else {
            ss[c] = make_float2(0.f, 0.f);
        }
    }

    // ---- staging role: threads 0..195 own 8 consecutive floats of a slab
    const bool act = tid < (SLAB / 8);               // 196
    const int fb  = tid * 8;
    const int cl0 = fb / HWS;                        // channel-in-slab 0..31
    const int hw0 = fb - cl0 * HWS;
    const int jw  = (hw0 + 8 <= HWS) ? 8 : (HWS - hw0);
    int addrs[8];
    #pragma unroll
    for (int j = 0; j < 8; j++) {
        int hw = hw0 + j, cl = cl0;
        if (hw >= HWS) { hw -= HWS; cl += 1; }
        const int rot = ((cl >> 3) + (hw >> 2)) & 3;      // bank swizzle
        addrs[j] = hw * BK + rot * 8 + (cl & 7);
    }
    const float* xs = x + (size_t)b * (CIN * HWS) + (size_t)cbase * HWS + fb;

    // ---- compute role: 4 waves, wave = 48 Cout rows x all 64 cols
    const int lane = tid & 63;
    const int mg   = tid >> 6;        // 0..3: row group mg*48
    const int l15  = lane & 15;
    const int q    = lane >> 4;

    int bad[4];                       // B-frag LDS addrs per col-tile
    #pragma unroll
    for (int ct = 0; ct < 4; ct++) {
        int hwct = ct * 16 + l15;
        if (hwct > 48) hwct = 48;     // ct=3 lanes 1..15 dup col 48
        bad[ct] = hwct * BK + ((q + (hwct >> 2)) & 3) * 8;
    }

    const bf16* apL = Wb + (size_t)(mg * 3) * 512 + (size_t)lane * 8;

    f32x4 acc[3][4];
    #pragma unroll
    for (int mt = 0; mt < 3; mt++)
        #pragma unroll
        for (int ct = 0; ct < 4; ct++) acc[mt][ct] = (f32x4)(0.f);

    // prologue: slab0 temp + parity x prefetch; A parity preload
    f32x4 t0 = (f32x4)(0.f), t1 = (f32x4)(0.f);
    f32x4 xvA0 = (f32x4)(0.f), xvA1 = (f32x4)(0.f);
    f32x4 xvB0 = (f32x4)(0.f), xvB1 = (f32x4)(0.f);
    if (act) {
        t0   = *(const f32x4*)(xs);
        t1   = *(const f32x4*)(xs + 4);
        xvA0 = *(const f32x4*)(xs + SLAB);
        xvA1 = *(const f32x4*)(xs + SLAB + 4);
        xvB0 = *(const f32x4*)(xs + 2 * SLAB);
        xvB1 = *(const f32x4*)(xs + 2 * SLAB + 4);
    }
    bf16x8 arE[3], arO[3];
    #pragma unroll
    for (int mt = 0; mt < 3; mt++) {
        arE[mt] = *(const bf16x8*)(apL + ((size_t)kbase * 6144) + (size_t)(mt * 512));
        arO[mt] = *(const bf16x8*)(apL + ((size_t)(kbase + 1) * 6144) + (size_t)(mt * 512));
    }

    __syncthreads();   // ss ready

    // stage slab 0 into bt[0]
    if (act) {
        const float2 s0 = ss[cl0];
        const float2 s1 = ss[cl0 + 1];
        #pragma unroll
        for (int j = 0; j < 8; j++) {
            const float xj = (j < 4) ? t0[j] : t1[j - 4];
            const float sc = (j >= jw) ? s1.x : s0.x;
            const float sh = (j >= jw) ? s1.y : s0.y;
            bt[0][addrs[j]] = (bf16)fmaxf(fmaf(xj, sc, sh), 0.f);
        }
    }
    asm volatile("s_waitcnt lgkmcnt(0)" ::: "memory");
    __builtin_amdgcn_s_barrier();
    __builtin_amdgcn_sched_barrier(0);

    // one granule (local index g): read bt[p]; stage slab g+1 -> bt[p^1];
    // x prefetch g+3 into this parity's slot; barrier; 12 MFMA; A reload g+2.
    auto STEP = [&](int p, int g, f32x4& xv0, f32x4& xv1, bf16x8 (&ar)[3]) {
        bf16x8 bf0 = *(const bf16x8*)&bt[p][bad[0]];
        bf16x8 bf1 = *(const bf16x8*)&bt[p][bad[1]];
        bf16x8 bf2 = *(const bf16x8*)&bt[p][bad[2]];
        bf16x8 bf3 = *(const bf16x8*)&bt[p][bad[3]];
        if (act) {
            int sl = g + 1; if (sl > NL - 1) sl = NL - 1;   // tail-safe
            const int cb = sl * BK;
            const float2 s0 = ss[cb + cl0];
            const float2 s1 = ss[cb + cl0 + 1];
            #pragma unroll
            for (int j = 0; j < 8; j++) {
                const float xj = (j < 4) ? xv0[j] : xv1[j - 4];
                const float sc = (j >= jw) ? s1.x : s0.x;
                const float sh = (j >= jw) ? s1.y : s0.y;
                bt[p ^ 1][addrs[j]] = (bf16)fmaxf(fmaf(xj, sc, sh), 0.f);
            }
            int ln = g + 3; if (ln > NL - 1) ln = NL - 1;
            xv0 = *(const f32x4*)(xs + (size_t)ln * SLAB);
            xv1 = *(const f32x4*)(xs + (size_t)ln * SLAB + 4);
        }
        asm volatile("s_waitcnt lgkmcnt(0)" ::: "memory");
        __builtin_amdgcn_s_barrier();
        __builtin_amdgcn_sched_barrier(0);
        #pragma unroll
        for (int mt = 0; mt < 3; mt++) {
            acc[mt][0] = __builtin_amdgcn_mfma_f32_16x16x32_bf16(ar[mt], bf0, acc[mt][0], 0, 0, 0);
            acc[mt][1] = __builtin_amdgcn_mfma_f32_16x16x32_bf16(ar[mt], bf1, acc[mt][1], 0, 0, 0);
            acc[mt][2] = __builtin_amdgcn_mfma_f32_16x16x32_bf16(ar[mt], bf2, acc[mt][2], 0, 0, 0);
            acc[mt][3] = __builtin_amdgcn_mfma_f32_16x16x32_bf16(ar[mt], bf3, acc[mt][3], 0, 0, 0);
        }
        int tk = g + 2; if (tk > NL - 1) tk = NL - 1;
        #pragma unroll
        for (int mt = 0; mt < 3; mt++)
            ar[mt] = *(const bf16x8*)(apL + (size_t)(kbase + tk) * 6144 + (size_t)(mt * 512));
    };

    // 5 parity pairs + 1 tail = 11 granules. Rolled; ring slots static.
    #pragma unroll 1
    for (int it = 0; it < NL / 2; ++it) {
        STEP(0, 2 * it,     xvA0, xvA1, arE);
        STEP(1, 2 * it + 1, xvB0, xvB1, arO);
    }
    STEP(0, NL - 1, xvA0, xvA1, arE);

    // epilogue: atomic accumulate partial sums. col=l15 -> hw, row=q*4+r.
    float* ob = out + (size_t)b * (COUT * HWS);
    #pragma unroll
    for (int mt = 0; mt < 3; mt++) {
        const int row0 = mg * 48 + mt * 16 + q * 4;
        #pragma unroll
        for (int ct = 0; ct < 4; ct++) {
            const int hw = ct * 16 + l15;
            if (hw < HWS) {
                #pragma unroll
                for (int r = 0; r < 4; r++)
                    atomicAdd(&ob[(size_t)(row0 + r) * HWS + hw], acc[mt][ct][r]);
            }
        }
    }
}

extern "C" void kernel_launch(void* const* d_in, const int* in_sizes, int n_in,
                              void* d_out, int out_size, void* d_ws, size_t ws_size,
                              hipStream_t stream) {
    const float* x     = (const float*)d_in[0];
    const float* gamma = (const float*)d_in[1];
    const float* beta  = (const float*)d_in[2];
    const float* rmean = (const float*)d_in[3];
    const float* rvar  = (const float*)d_in[4];
    const float* W     = (const float*)d_in[5];
    float* out = (float*)d_out;

    bf16* Wb = (bf16*)d_ws;                        // 811,008 B, L2-resident

    hipMemsetAsync(out, 0, (size_t)out_size, stream);   // atomics accumulate
    w_repack_kernel<<<dim3(198), dim3(256), 0, stream>>>(W, Wb);
    fused_kernel<<<dim3(NCHUNK * 256), dim3(256), 0, stream>>>(
        x, gamma, beta, rmean, rvar, Wb, out);
}

// Round 7
// 180.169 us; speedup vs baseline: 1.4458x; 1.4458x over previous
//
#include <hip/hip_runtime.h>
#include <hip/hip_bf16.h>

// out[b,o,hw] = sum_c W[o,c] * relu(x[b,c,hw]*scale[c] + shift[c])
// B=256, Cin=2112, Cout=192, HW=49, fp32 in HBM, bf16 MFMA internally.
//
// R14: READ-SIDE transpose. Every LDS-staged variant (R8/R9/R11) sat at
// fused ~60-65us invariant to barrier count / grouping / occupancy; the
// never-ablated invariant was the staging path (8x ds_write_b16 scatter +
// write-side BN/cvt + swizzle). R14 deletes it: x is staged fp32 LINEAR
// (1 global_load_dwordx4 -> 1 ds_write_b128 per act thread per granule,
// load issued 2 granules early, write 1 granule early), and the transpose
// happens on the READ side: each compute lane reads its 8 k-elems as 8
// stride-49 ds_read_b32 (bank math: (8q+17j+hw)%32 -> 2 lanes/bank = free)
// + 4 contiguous b128 BN-pair reads, then BN+ReLU+cvt in-register feeding
// the MFMA. MFMA layout / A-ring / epilogue identical to proven R8/R9.
// One lgkmcnt(0)+s_barrier per granule; no vmcnt drains (compiler waits
// on the 2-granule-slack loads at use).

#define CIN    2112
#define COUT   192
#define HWS    49
#define BK     32
#define NK32   (CIN / BK)          // 66 granules
#define EPSV   1e-5f
#define SLABF  (BK * HWS)          // 1568 floats per granule slab

typedef __bf16 bf16;
typedef __attribute__((ext_vector_type(8))) __bf16 bf16x8;
typedef __attribute__((ext_vector_type(4))) float  f32x4;

// ---------- kernel 1: W fp32 -> bf16 in A-fragment order (unchanged) ----------
__global__ __launch_bounds__(256)
void w_repack_kernel(const float* __restrict__ W, bf16* __restrict__ Wb) {
    const int t = blockIdx.x * 256 + threadIdx.x;       // 66*12*64 = 50688
    if (t >= NK32 * 12 * 64) return;
    const int lane = t & 63;
    const int gmt  = (t >> 6) % 12;
    const int ks   = t / (12 * 64);
    const int row  = gmt * 16 + (lane & 15);
    const int k    = ks * BK + (lane >> 4) * 8;
    const float* src = W + (size_t)row * CIN + k;
    f32x4 a = *(const f32x4*)src;
    f32x4 c = *(const f32x4*)(src + 4);
    bf16x8 o;
    #pragma unroll
    for (int j = 0; j < 4; j++) { o[j] = (bf16)a[j]; o[j + 4] = (bf16)c[j]; }
    *(bf16x8*)(Wb + (size_t)t * 8) = o;
}

// ---------- kernel 2: fused BN+ReLU+GEMM, fp32 linear LDS, read-side pack ----------
__global__ __launch_bounds__(512, 2)
void fused_kernel(const float* __restrict__ x,
                  const float* __restrict__ gamma,
                  const float* __restrict__ beta,
                  const float* __restrict__ rmean,
                  const float* __restrict__ rvar,
                  const bf16* __restrict__ Wb,
                  float* __restrict__ out)
{
    __shared__ __align__(16) float2 ss[CIN];         // BN scale/shift pairs
    __shared__ __align__(16) float  xb[2][SLABF];    // double-buffered fp32 slab

    const int tid = threadIdx.x;
    const int b   = blockIdx.x;

    // BN params -> LDS
    for (int c = tid; c < CIN; c += 512) {
        float inv = rsqrtf(rvar[c] + EPSV);
        float s   = gamma[c] * inv;
        ss[c] = make_float2(s, beta[c] - rmean[c] * s);
    }

    // ---- staging role: threads 0..391 own 4 consecutive floats of a slab
    const bool act = tid < (SLABF / 4);              // 392
    const float* xg = x + (size_t)b * (CIN * HWS) + tid * 4;
    float* w0 = &xb[0][tid * 4];
    float* w1 = &xb[1][tid * 4];

    // ---- compute role: 8 waves = 4 M-groups x 2 N-groups (R8-identical)
    const int lane = tid & 63;
    const int wv   = tid >> 6;
    const int mg   = wv & 3;          // 48 Cout rows
    const int ng   = wv >> 2;         // 32 hw cols
    const int l15  = lane & 15;
    const int q    = lane >> 4;

    const int hwc0 = ng * 32 + l15;               // <= 47, always valid
    int hwc1 = ng * 32 + 16 + l15;
    if (hwc1 > 48) hwc1 = 48;                     // dup col 48 (discarded)
    const int rb0 = q * 8 * HWS + hwc0;           // float idx of (j=0, col0)
    const int rb1 = q * 8 * HWS + hwc1;

    const bf16* apL = Wb + (size_t)(mg * 3) * 512 + (size_t)lane * 8;

    f32x4 acc[3][2];
    #pragma unroll
    for (int mt = 0; mt < 3; mt++) { acc[mt][0] = (f32x4)(0.f); acc[mt][1] = (f32x4)(0.f); }

    // A-frag parity ring, preloaded granules 0,1
    bf16x8 arE[3], arO[3];
    #pragma unroll
    for (int mt = 0; mt < 3; mt++) {
        arE[mt] = *(const bf16x8*)(apL + (size_t)(mt * 512));
        arO[mt] = *(const bf16x8*)(apL + (size_t)(6144 + mt * 512));
    }

    // prologue: slab0 -> LDS buf0 (via reg), slab1 -> reg slot B
    f32x4 xrA = (f32x4)(0.f), xrB = (f32x4)(0.f);
    if (act) {
        xrA = *(const f32x4*)(xg);                 // slab 0
        xrB = *(const f32x4*)(xg + SLABF);         // slab 1
        *(f32x4*)w0 = xrA;                         // stage slab 0 linear
    }
    __syncthreads();   // ss + xb[0] ready; xrA slot now free

    // one granule g: read buf[g&1] (8+8 stride-49 b32 + 4 b128 BN pairs);
    // stage slab g+1 from reg slot xw -> buf[g&1 ^ 1]; load slab g+2 -> xl;
    // build bfrags in-register; 6 MFMA; A-reload g+2; lgkm drain; barrier.
    auto STEP = [&](int g, bf16x8 (&ar)[3], f32x4& xw, f32x4& xl) {
        const int p = g & 1;
        const float* bp = &xb[p][0];

        float xf0[8], xf1[8];
        #pragma unroll
        for (int j = 0; j < 8; j++) {
            xf0[j] = bp[rb0 + j * HWS];
            xf1[j] = bp[rb1 + j * HWS];
        }
        f32x4 sv[4];                               // 8 BN float2 pairs
        {
            const f32x4* ssv = (const f32x4*)&ss[g * BK + q * 8];
            #pragma unroll
            for (int k = 0; k < 4; k++) sv[k] = ssv[k];
        }

        if (act) {
            if (g < NK32 - 1) *(f32x4*)((p == 0) ? w1 : w0) = xw;   // stage g+1
            int ln = g + 2; if (ln > NK32 - 1) ln = NK32 - 1;
            xl = *(const f32x4*)(xg + (size_t)ln * SLABF);          // load g+2
        }

        bf16x8 b0, b1;
        #pragma unroll
        for (int j = 0; j < 8; j++) {
            const float sc = sv[j >> 1][(j & 1) * 2];
            const float sh = sv[j >> 1][(j & 1) * 2 + 1];
            b0[j] = (bf16)fmaxf(fmaf(xf0[j], sc, sh), 0.f);
            b1[j] = (bf16)fmaxf(fmaf(xf1[j], sc, sh), 0.f);
        }
        #pragma unroll
        for (int mt = 0; mt < 3; mt++) {
            acc[mt][0] = __builtin_amdgcn_mfma_f32_16x16x32_bf16(ar[mt], b0, acc[mt][0], 0, 0, 0);
            acc[mt][1] = __builtin_amdgcn_mfma_f32_16x16x32_bf16(ar[mt], b1, acc[mt][1], 0, 0, 0);
        }
        int tk = g + 2; if (tk > NK32 - 1) tk = NK32 - 1;
        #pragma unroll
        for (int mt = 0; mt < 3; mt++)
            ar[mt] = *(const bf16x8*)(apL + (size_t)tk * 6144 + (size_t)(mt * 512));

        asm volatile("s_waitcnt lgkmcnt(0)" ::: "memory");
        __builtin_amdgcn_s_barrier();
        __builtin_amdgcn_sched_barrier(0);
    };

    // rolled pair loop: 33 pairs = 66 granules; all ring slots static.
    #pragma unroll 1
    for (int it = 0; it < NK32 / 2; ++it) {
        STEP(2 * it,     arE, xrB, xrA);   // even: write slot B, load into A
        STEP(2 * it + 1, arO, xrA, xrB);   // odd:  write slot A, load into B
    }

    // epilogue: C/D layout col=l15 -> hw, row=q*4+r (R8-proven). Disjoint.
    float* ob = out + (size_t)b * (COUT * HWS);
    const int hw1 = ng * 32 + 16 + l15;            // unclamped for predicate
    #pragma unroll
    for (int mt = 0; mt < 3; mt++) {
        const int row0 = mg * 48 + mt * 16 + q * 4;
        #pragma unroll
        for (int r = 0; r < 4; r++)
            ob[(size_t)(row0 + r) * HWS + hwc0] = acc[mt][0][r];
        if (hw1 < HWS) {
            #pragma unroll
            for (int r = 0; r < 4; r++)
                ob[(size_t)(row0 + r) * HWS + hw1] = acc[mt][1][r];
        }
    }
}

extern "C" void kernel_launch(void* const* d_in, const int* in_sizes, int n_in,
                              void* d_out, int out_size, void* d_ws, size_t ws_size,
                              hipStream_t stream) {
    const float* x     = (const float*)d_in[0];
    const float* gamma = (const float*)d_in[1];
    const float* beta  = (const float*)d_in[2];
    const float* rmean = (const float*)d_in[3];
    const float* rvar  = (const float*)d_in[4];
    const float* W     = (const float*)d_in[5];
    float* out = (float*)d_out;

    bf16* Wb = (bf16*)d_ws;                        // 811,008 B, L2-resident

    w_repack_kernel<<<dim3(198), dim3(256), 0, stream>>>(W, Wb);
    fused_kernel<<<dim3(256), dim3(512), 0, stream>>>(
        x, gamma, beta, rmean, rvar, Wb, out);
}